// Round 6
// baseline (1694.606 us; speedup 1.0000x reference)
//
#include <hip/hip_runtime.h>

// ---------- constants ----------
#define B_   64
#define P_   196
#define ENC_ 512
#define ATT_ 256
#define DEC_ 256
#define EMB_ 256
#define V_   10000
#define T_   44
#define G4_  1024          // 4*DEC
#define XW_  768           // EMB+ENC (W_ih inner dim)
#define A1N_ 26624         // att1h per-b u32 count: 128 a2 * 208 p
#define EWR_ 98            // encW p2 rows (196/2)

using short8 = __attribute__((ext_vector_type(8))) short;
using half8  = __attribute__((ext_vector_type(8))) _Float16;
using f32x4  = __attribute__((ext_vector_type(4))) float;
typedef _Float16 f16x2 __attribute__((ext_vector_type(2)));

__device__ __forceinline__ unsigned short f2bf(float f) {
    unsigned int u = __float_as_uint(f);
    unsigned int r = (u + 0x7fffu + ((u >> 16) & 1u)) >> 16;
    return (unsigned short)r;
}

__device__ __forceinline__ unsigned int pkh2(float a, float b) {
    f16x2 t; t.x = (_Float16)a; t.y = (_Float16)b;
    return __builtin_bit_cast(unsigned int, t);
}

// fp16x2 dot with fp32 accumulate (single V_DOT2_F32_F16 where available)
__device__ __forceinline__ float fdot2u(unsigned int wbits, f16x2 xv, float acc) {
    f16x2 wv = __builtin_bit_cast(f16x2, wbits);
#if __has_builtin(__builtin_amdgcn_fdot2)
    return __builtin_amdgcn_fdot2(wv, xv, acc, false);
#else
    acc = fmaf((float)wv.x, (float)xv.x, acc);
    acc = fmaf((float)wv.y, (float)xv.y, acc);
    return acc;
#endif
}

// raw barrier: drains LDS ops only; global loads stay in flight (T4).
__device__ __forceinline__ void bar() {
    asm volatile("s_waitcnt lgkmcnt(0)" ::: "memory");
    __builtin_amdgcn_s_barrier();
    asm volatile("" ::: "memory");
}

// ---------- generic 32x32 transpose: dst[k*N + n] = src[n*stride + off + k] ----------
__global__ void k_transpose(const float* __restrict__ src, float* __restrict__ dst,
                            int N, int stride, int off) {
    __shared__ float t[32][33];
    int k0 = blockIdx.x * 32, n0 = blockIdx.y * 32;
    int tx = threadIdx.x & 31, ty = threadIdx.x >> 5;
    for (int r = ty; r < 32; r += 8)
        t[r][tx] = src[(size_t)(n0 + r) * stride + off + k0 + tx];
    __syncthreads();
    for (int r = ty; r < 32; r += 8)
        dst[(size_t)(k0 + r) * N + n0 + tx] = t[tx][r];
}

// ---------- pack W_dec_att [a][d] -> WdaP4[d4*256+a] = {W[a][4d4..4d4+3]} ----------
__global__ __launch_bounds__(256) void k_packWda(const float* __restrict__ Wda,
                                                 float4* __restrict__ WdaP4) {
    int d4 = blockIdx.x, a = threadIdx.x;
    float4 v;
    v.x = Wda[(size_t)a * DEC_ + 4 * d4 + 0];
    v.y = Wda[(size_t)a * DEC_ + 4 * d4 + 1];
    v.z = Wda[(size_t)a * DEC_ + 4 * d4 + 2];
    v.w = Wda[(size_t)a * DEC_ + 4 * d4 + 3];
    WdaP4[(size_t)d4 * 256 + a] = v;
}

// ---------- pack W_hh fp16 pairs: WhhP[d2*1024 + j] = h2{W_hh[j][2d2], W_hh[j][2d2+1]} ----------
// grid: (128, 4) x 256
__global__ __launch_bounds__(256) void k_packWhh(const float* __restrict__ Whh,
                                                 unsigned int* __restrict__ WhhP) {
    int d2 = blockIdx.x;
    int j = blockIdx.y * 256 + threadIdx.x;
    WhhP[(size_t)d2 * 1024 + j] =
        pkh2(Whh[(size_t)j * DEC_ + 2 * d2], Whh[(size_t)j * DEC_ + 2 * d2 + 1]);
}

// ---------- encW[b][p2][j] = h2{ C[2p2][j], C[2p2+1][j] }, C[p][j] = enc[b,p,:].W_ih[j,0:512] ----------
// fp16 MFMA GEMM, 128x128 tiles. grid (8 n-tiles, 2 m-tiles, 64 b), 256 thr.
__global__ __launch_bounds__(256) void k_encW(
        const float* __restrict__ enc, const float* __restrict__ Wih,
        unsigned int* __restrict__ encW) {
    int n0 = blockIdx.x * 128, m0 = blockIdx.y * 128, b = blockIdx.z;
    __shared__ __align__(16) unsigned short At[128][40];
    __shared__ __align__(16) unsigned short Bt[128][40];
    int tid = threadIdx.x;
    int lane = tid & 63, w = tid >> 6;
    int wm = (w & 1) * 64, wn = (w >> 1) * 64;
    f32x4 acc[4][4];
#pragma unroll
    for (int i = 0; i < 4; i++)
#pragma unroll
        for (int j = 0; j < 4; j++) acc[i][j] = (f32x4){0.f, 0.f, 0.f, 0.f};

    for (int k0 = 0; k0 < ENC_; k0 += 32) {
#pragma unroll
        for (int l = 0; l < 2; l++) {
            int idx = l * 256 + tid;          // 0..511
            int r = idx >> 2, kcf = (idx & 3) * 8;
            uint4 av = make_uint4(0u, 0u, 0u, 0u);
            int p = m0 + r;
            if (p < P_) {
                const float* ap = enc + ((size_t)b * P_ + p) * ENC_ + k0 + kcf;
                float4 f0 = *reinterpret_cast<const float4*>(ap);
                float4 f1 = *reinterpret_cast<const float4*>(ap + 4);
                av.x = pkh2(f0.x, f0.y); av.y = pkh2(f0.z, f0.w);
                av.z = pkh2(f1.x, f1.y); av.w = pkh2(f1.z, f1.w);
            }
            *reinterpret_cast<uint4*>(&At[r][kcf]) = av;
            const float* bp = Wih + (size_t)(n0 + r) * XW_ + k0 + kcf;
            float4 g0 = *reinterpret_cast<const float4*>(bp);
            float4 g1 = *reinterpret_cast<const float4*>(bp + 4);
            uint4 bv;
            bv.x = pkh2(g0.x, g0.y); bv.y = pkh2(g0.z, g0.w);
            bv.z = pkh2(g1.x, g1.y); bv.w = pkh2(g1.z, g1.w);
            *reinterpret_cast<uint4*>(&Bt[r][kcf]) = bv;
        }
        __syncthreads();
        int qk = (lane >> 4) * 8, fr = lane & 15;
        half8 a[4], bb[4];
#pragma unroll
        for (int i = 0; i < 4; i++) {
            a[i]  = *reinterpret_cast<const half8*>(&At[wm + i * 16 + fr][qk]);
            bb[i] = *reinterpret_cast<const half8*>(&Bt[wn + i * 16 + fr][qk]);
        }
#pragma unroll
        for (int i = 0; i < 4; i++)
#pragma unroll
            for (int j = 0; j < 4; j++)
                acc[i][j] = __builtin_amdgcn_mfma_f32_16x16x32_f16(a[i], bb[j], acc[i][j], 0, 0, 0);
        __syncthreads();
    }
    unsigned int* eb = encW + (size_t)b * (EWR_ * 1024);
    int col = lane & 15, qr = (lane >> 4) * 4;
#pragma unroll
    for (int j = 0; j < 4; j++) {
        int n = n0 + wn + j * 16 + col;
#pragma unroll
        for (int i = 0; i < 4; i++) {
            int row0 = m0 + wm + i * 16 + qr;     // even
            if (row0 < P_)
                eb[(size_t)(row0 >> 1) * 1024 + n] = pkh2(acc[i][j][0], acc[i][j][1]);
            if (row0 + 2 < P_)
                eb[(size_t)((row0 >> 1) + 1) * 1024 + n] = pkh2(acc[i][j][2], acc[i][j][3]);
        }
    }
}

// ---------- fp32 -> bf16 convert ----------
__global__ void k_cvt(const float* __restrict__ src, unsigned short* __restrict__ dst, int n) {
    int i = blockIdx.x * 256 + threadIdx.x;
    if (i < n) dst[i] = f2bf(src[i]);
}

// ---------- h0/c0 from mean-pooled encoder ----------
__global__ __launch_bounds__(256) void k_init_state(
        const float* __restrict__ enc,
        const float* __restrict__ W_init_h, const float* __restrict__ b_init_h,
        const float* __restrict__ W_init_c, const float* __restrict__ b_init_c,
        float* __restrict__ h0, float* __restrict__ c0) {
    int b = blockIdx.x, tid = threadIdx.x;
    __shared__ float avg[ENC_];
    for (int e = tid; e < ENC_; e += 256) {
        float s = 0.f;
        const float* p = enc + (size_t)b * P_ * ENC_ + e;
        for (int i = 0; i < P_; i++) s += p[(size_t)i * ENC_];
        avg[e] = s * (1.0f / (float)P_);
    }
    __syncthreads();
    int d = tid;  // 256 threads == DEC_
    float hs = b_init_h[d], cs = b_init_c[d];
    const float* wh = W_init_h + (size_t)d * ENC_;
    const float* wc = W_init_c + (size_t)d * ENC_;
    for (int e = 0; e < ENC_; e++) { float a = avg[e]; hs += a * wh[e]; cs += a * wc[e]; }
    h0[b * DEC_ + d] = hs;
    c0[b * DEC_ + d] = cs;
}

// ---------- att1h[b][a2(128)][208 p] = f16x2{ att1[2a2][p], att1[2a2+1][p] } ----------
// grid: 64 b * 4 a-tiles(64)
__global__ __launch_bounds__(256) void k_att1(
        const float* __restrict__ enc, const float* __restrict__ Wea,
        unsigned int* __restrict__ att1h) {
    int b = blockIdx.x >> 2, a0 = (blockIdx.x & 3) * 64;
    __shared__ float encT[32][257];   // [e_local][p] padded
    __shared__ float Wt[64][32];      // [a_local][e_local]
    int tid = threadIdx.x;
    int pl = tid & 63, ia = tid >> 6;
    float acc[16][4];
#pragma unroll
    for (int k = 0; k < 16; k++)
#pragma unroll
        for (int qq = 0; qq < 4; qq++) acc[k][qq] = 0.f;

    for (int e0 = 0; e0 < ENC_; e0 += 32) {
        {
            int j = tid & 31, pr = tid >> 5;
            for (int pass = 0; pass < 32; pass++) {
                int p = pr + pass * 8;
                float v = 0.f;
                if (p < P_) v = enc[((size_t)b * P_ + p) * ENC_ + e0 + j];
                encT[j][p] = v;
            }
            int r = tid >> 2, c0 = (tid & 3) * 8;
#pragma unroll
            for (int i = 0; i < 8; i++)
                Wt[r][c0 + i] = Wea[(size_t)(a0 + r) * ENC_ + e0 + c0 + i];
        }
        __syncthreads();
        for (int e = 0; e < 32; e++) {
            float e0v = encT[e][pl], e1v = encT[e][pl + 64];
            float e2v = encT[e][pl + 128], e3v = encT[e][pl + 192];
#pragma unroll
            for (int k = 0; k < 16; k++) {
                float w = Wt[ia * 16 + k][e];
                acc[k][0] += w * e0v; acc[k][1] += w * e1v;
                acc[k][2] += w * e2v; acc[k][3] += w * e3v;
            }
        }
        __syncthreads();
    }
#pragma unroll
    for (int k = 0; k < 16; k += 2)
#pragma unroll
        for (int qq = 0; qq < 4; qq++) {
            int p = pl + 64 * qq;
            int a = a0 + ia * 16 + k;
            if (p < P_)
                att1h[(size_t)b * A1N_ + (size_t)(a >> 1) * 208 + p] =
                    pkh2(acc[k][qq], acc[k + 1][qq]);
        }
}

// ---------- embW[(t*64+b)][j] = b_ih[j]+b_hh[j] + sum_e emb[cap(b,t)][e]*W_ih[j][512+e] ----------
__global__ __launch_bounds__(256) void k_embW(
        const int* __restrict__ caption, const float* __restrict__ embedding,
        const float* __restrict__ WiheT, const float* __restrict__ b_ih,
        const float* __restrict__ b_hh, float* __restrict__ embW) {
    int r0 = blockIdx.x * 16, tid = threadIdx.x;
    __shared__ float embL[16][256];
    __shared__ int capL[16];
    if (tid < 16) {
        int r = r0 + tid, t = r >> 6, b = r & 63;
        capL[tid] = caption[b * T_ + t];
    }
    __syncthreads();
#pragma unroll
    for (int lr = 0; lr < 16; lr++)
        embL[lr][tid] = embedding[(size_t)capL[lr] * EMB_ + tid];
    __syncthreads();
    float base0 = b_ih[tid] + b_hh[tid];
    float base1 = b_ih[tid + 256] + b_hh[tid + 256];
    float base2 = b_ih[tid + 512] + b_hh[tid + 512];
    float base3 = b_ih[tid + 768] + b_hh[tid + 768];
    float acc[16][4];
#pragma unroll
    for (int lr = 0; lr < 16; lr++) {
        acc[lr][0] = base0; acc[lr][1] = base1; acc[lr][2] = base2; acc[lr][3] = base3;
    }
    for (int e = 0; e < EMB_; e++) {
        const float* wr = WiheT + (size_t)e * G4_ + tid;
        float w0 = wr[0], w1 = wr[256], w2 = wr[512], w3 = wr[768];
#pragma unroll
        for (int lr = 0; lr < 16; lr++) {
            float ev = embL[lr][e];
            acc[lr][0] += w0 * ev; acc[lr][1] += w1 * ev;
            acc[lr][2] += w2 * ev; acc[lr][3] += w3 * ev;
        }
    }
#pragma unroll
    for (int lr = 0; lr < 16; lr++) {
        float* o = embW + (size_t)(r0 + lr) * G4_ + tid;
        o[0] = acc[lr][0]; o[256] = acc[lr][1]; o[512] = acc[lr][2]; o[768] = acc[lr][3];
    }
}

// ---------- the sequential recurrence: one block (1024 thr = 16 waves, 4 waves/EU) per b ----------
// P3 eliminated via encW factorization; att1 held in registers; gates via j-ownership uint4 loads.
__global__ __launch_bounds__(1024, 4) void k_recur(
        const unsigned int* __restrict__ att1h, const float4* __restrict__ WdaP4,
        const float* __restrict__ W_full, const unsigned int* __restrict__ WhhP,
        const unsigned int* __restrict__ encW, const float* __restrict__ embW,
        const float* __restrict__ h0, const float* __restrict__ c0,
        unsigned short* __restrict__ Hbf, float* __restrict__ out_alpha) {
    int b = blockIdx.x, tid = threadIdx.x;
    int q = tid >> 8;          // 0..3
    int r = tid & 255;
    int j4 = tid & 255;        // uint4 column group: j = 4*j4 + comp
    int sub = (tid >> 8) & 1;  // half-split within role
    bool isW = tid >= 512;     // role: 0 = encW (alpha) part, 1 = W_hh part

    __shared__ __align__(16) float h_l[DEC_];
    __shared__ __align__(16) float att2_l[ATT_];
    __shared__ __align__(16) float wf_l[ATT_];
    __shared__ __align__(4) _Float16 hh_h[DEC_];
    __shared__ __align__(4) _Float16 alpha_h[212];
    __shared__ float p1[4][256];
    __shared__ float p2[4][256];
    __shared__ __align__(16) float4 pj[2][256];
    __shared__ __align__(16) float4 pw[2][256];
    __shared__ float gl[G4_];
    __shared__ float red_l[4];

    // att1 rows for this thread's (q, r), loop-invariant over t -> registers (32 u32)
    unsigned int a1r[32];
    {
        int rc = (r < 208) ? r : 207;
        const unsigned int* a1g = att1h + (size_t)b * A1N_ + (size_t)(q * 32) * 208 + rc;
#pragma unroll
        for (int i = 0; i < 32; i++) a1r[i] = a1g[(size_t)i * 208];
    }
    if (tid < 256) {
        float hv = h0[b * DEC_ + tid];
        h_l[tid] = hv;
        hh_h[tid] = (_Float16)hv;
        wf_l[tid] = W_full[tid];
    }
    if (tid < 212) alpha_h[tid] = (_Float16)0.f;
    float c = (tid < 256) ? c0[b * DEC_ + tid] : 0.f;
    __syncthreads();

    const uint4* encW4 = reinterpret_cast<const uint4*>(encW + (size_t)b * (EWR_ * 1024));
    const uint4* whh4  = reinterpret_cast<const uint4*>(WhhP);

    for (int t = 0; t < T_; ++t) {
        // ---- P1: att2 partial over d in [q*64,(q+1)*64), thread r = a (fp32)
        float a2 = 0.f;
#pragma unroll 4
        for (int i = 0; i < 16; i++) {
            int d4 = q * 16 + i;
            float4 w = WdaP4[(size_t)d4 * 256 + r];
            float4 h4 = *reinterpret_cast<const float4*>(&h_l[4 * d4]);
            a2 += w.x * h4.x + w.y * h4.y + w.z * h4.z + w.w * h4.w;
        }
        p1[q][r] = a2;
        bar();
        if (tid < 256) att2_l[tid] = p1[0][tid] + p1[1][tid] + p1[2][tid] + p1[3][tid];
        bar();

        // ---- P2: score partial over a-pairs in [q*32,(q+1)*32), att1 from registers
        float sp = 0.f;
#pragma unroll
        for (int i = 0; i < 32; i++) {
            int a2i = q * 32 + i;
            f16x2 av = __builtin_bit_cast(f16x2, a1r[i]);
            float2 t2 = *reinterpret_cast<const float2*>(&att2_l[2 * a2i]);
            float2 w4 = *reinterpret_cast<const float2*>(&wf_l[2 * a2i]);
            sp += fmaxf((float)av.x + t2.x, 0.f) * w4.x +
                  fmaxf((float)av.y + t2.y, 0.f) * w4.y;
        }
        p2[q][r] = sp;
        bar();

        // ---- softmax (no max-subtraction; fp32 exp safe for these score magnitudes)
        float ex = 0.f;
        if (tid < 256) {
            float s = p2[0][tid] + p2[1][tid] + p2[2][tid] + p2[3][tid];
            ex = (tid < P_) ? __expf(s) : 0.f;
            float sm = ex;
#pragma unroll
            for (int off = 32; off; off >>= 1) sm += __shfl_xor(sm, off);
            if ((tid & 63) == 0) red_l[tid >> 6] = sm;
        }
        bar();
        if (tid < 256) {
            float sm = red_l[0] + red_l[1] + red_l[2] + red_l[3];
            float alpha = ex / sm;           // == 0 for tid >= P_
            if (tid < 208) alpha_h[tid] = (_Float16)alpha;
            if (tid < P_) out_alpha[(size_t)b * (T_ * P_) + t * P_ + tid] = alpha;
        }
        // embW prefetch for this thread's j = tid (consumed in gl stage)
        float ewj = embW[((size_t)t * B_ + b) * G4_ + tid];
        bar();

        // ---- P4': gate partials, j-ownership (4 j's per thread), role-split halves
        float4 acc = {0.f, 0.f, 0.f, 0.f};
        if (!isW) {
            int p2b = sub * 49;
#pragma unroll 7
            for (int i = 0; i < 49; i++) {
                int pp = p2b + i;
                uint4 w = encW4[(size_t)pp * 256 + j4];
                f16x2 al = *reinterpret_cast<const f16x2*>(&alpha_h[2 * pp]);
                acc.x = fdot2u(w.x, al, acc.x);
                acc.y = fdot2u(w.y, al, acc.y);
                acc.z = fdot2u(w.z, al, acc.z);
                acc.w = fdot2u(w.w, al, acc.w);
            }
            pj[sub][j4] = acc;
        } else {
            int d2b = sub * 64;
#pragma unroll 8
            for (int i = 0; i < 64; i++) {
                int dd = d2b + i;
                uint4 w = whh4[(size_t)dd * 256 + j4];
                f16x2 h2v = *reinterpret_cast<const f16x2*>(&hh_h[2 * dd]);
                acc.x = fdot2u(w.x, h2v, acc.x);
                acc.y = fdot2u(w.y, h2v, acc.y);
                acc.z = fdot2u(w.z, h2v, acc.z);
                acc.w = fdot2u(w.w, h2v, acc.w);
            }
            pw[sub][j4] = acc;
        }
        bar();

        // ---- gl[j] = sum of 4 partials + embW (biases included in embW)
        {
            const float* pjF = reinterpret_cast<const float*>(pj);
            const float* pwF = reinterpret_cast<const float*>(pw);
            gl[tid] = pjF[tid] + pjF[1024 + tid] + pwF[tid] + pwF[1024 + tid] + ewj;
        }
        bar();

        // ---- P5: LSTM pointwise (torch gate order i,f,g,o)
        if (tid < 256) {
            float gi = gl[tid], gf = gl[tid + 256], gg = gl[tid + 512], go = gl[tid + 768];
            float i_g = 1.f / (1.f + __expf(-gi));
            float f_g = 1.f / (1.f + __expf(-gf));
            float g_g = tanhf(gg);
            float o_g = 1.f / (1.f + __expf(-go));
            c = f_g * c + i_g * g_g;
            float hn = o_g * tanhf(c);
            h_l[tid] = hn;
            hh_h[tid] = (_Float16)hn;
            Hbf[((size_t)t * B_ + b) * DEC_ + tid] = f2bf(hn);
        }
        bar();
    }
}

// ---------- logits: C[m][n] = H[m,:] . Wout[n,:] + b_out[n], bf16 MFMA ----------
__global__ __launch_bounds__(256) void k_logits(
        const unsigned short* __restrict__ Hbf, const unsigned short* __restrict__ Woutbf,
        const float* __restrict__ b_out, float* __restrict__ out) {
    int n0 = blockIdx.x * 128, m0 = blockIdx.y * 128;
    __shared__ __align__(16) unsigned short At[128][40];
    __shared__ __align__(16) unsigned short Bt[128][40];
    int tid = threadIdx.x;
    int lane = tid & 63, w = tid >> 6;
    int wm = (w & 1) * 64, wn = (w >> 1) * 64;
    f32x4 acc[4][4];
#pragma unroll
    for (int i = 0; i < 4; i++)
#pragma unroll
        for (int j = 0; j < 4; j++) acc[i][j] = (f32x4){0.f, 0.f, 0.f, 0.f};

    for (int k0 = 0; k0 < DEC_; k0 += 32) {
#pragma unroll
        for (int l = 0; l < 2; l++) {
            int idx = l * 256 + tid;         // 0..511
            int r = idx >> 2, kc = (idx & 3) * 8;
            uint4 av = *reinterpret_cast<const uint4*>(&Hbf[(size_t)(m0 + r) * DEC_ + k0 + kc]);
            *reinterpret_cast<uint4*>(&At[r][kc]) = av;
            uint4 bv = make_uint4(0u, 0u, 0u, 0u);
            if (n0 + r < V_)
                bv = *reinterpret_cast<const uint4*>(&Woutbf[(size_t)(n0 + r) * DEC_ + k0 + kc]);
            *reinterpret_cast<uint4*>(&Bt[r][kc]) = bv;
        }
        __syncthreads();
        int qk = (lane >> 4) * 8, fr = lane & 15;
        short8 a[4], bb[4];
#pragma unroll
        for (int i = 0; i < 4; i++) {
            a[i]  = *reinterpret_cast<const short8*>(&At[wm + i * 16 + fr][qk]);
            bb[i] = *reinterpret_cast<const short8*>(&Bt[wn + i * 16 + fr][qk]);
        }
#pragma unroll
        for (int i = 0; i < 4; i++)
#pragma unroll
            for (int j = 0; j < 4; j++)
                acc[i][j] = __builtin_amdgcn_mfma_f32_16x16x32_bf16(a[i], bb[j], acc[i][j], 0, 0, 0);
        __syncthreads();
    }
    int col = lane & 15, qr = (lane >> 4) * 4;
#pragma unroll
    for (int j = 0; j < 4; j++) {
        int n = n0 + wn + j * 16 + col;
        if (n < V_) {
            float bo = b_out[n];
#pragma unroll
            for (int i = 0; i < 4; i++)
#pragma unroll
                for (int rr = 0; rr < 4; rr++) {
                    int m = m0 + wm + i * 16 + qr + rr;
                    int t = m >> 6, bb2 = m & 63;
                    out[(size_t)bb2 * (T_ * V_) + (size_t)t * V_ + n] = acc[i][j][rr] + bo;
                }
        }
    }
}

// ---------- launch ----------
extern "C" void kernel_launch(void* const* d_in, const int* in_sizes, int n_in,
                              void* d_out, int out_size, void* d_ws, size_t ws_size,
                              hipStream_t stream) {
    const float* enc       = (const float*)d_in[0];
    const int*   caption   = (const int*)d_in[1];
    const float* W_enc_att = (const float*)d_in[2];
    const float* W_dec_att = (const float*)d_in[3];
    const float* W_full    = (const float*)d_in[4];
    const float* embedding = (const float*)d_in[5];
    const float* W_init_h  = (const float*)d_in[6];
    const float* b_init_h  = (const float*)d_in[7];
    const float* W_init_c  = (const float*)d_in[8];
    const float* b_init_c  = (const float*)d_in[9];
    const float* W_ih      = (const float*)d_in[10];
    const float* b_ih      = (const float*)d_in[11];
    const float* W_hh      = (const float*)d_in[12];
    const float* b_hh      = (const float*)d_in[13];
    const float* W_out     = (const float*)d_in[14];
    const float* b_out     = (const float*)d_in[15];

    float* ws = (float*)d_ws;
    float* h0    = ws;                    //      16384
    float* c0    = ws + 16384;            //      16384
    float* WdaP  = ws + 32768;            //      65536  [64 d4][256 a] float4
    float* WiheT = ws + 98304;            //     262144  [256 e][1024 j]
    float* WhhP  = ws + 360448;           //     131072  [128 d2][1024 j] u32 f16x2
    float* embW  = ws + 491520;           //    2883584  [t*64+b][1024]
    float* att1h = ws + 3375104;          //    1703936  [b][128 a2][208 p] f16x2 (u32)
    float* encW  = ws + 5079040;          //    6422528  [b][98 p2][1024 j] u32 f16x2
    unsigned short* Hbf    = (unsigned short*)(ws + 11501568);  // 2816*256 bf16 = 360448 fl
    unsigned short* Woutbf = (unsigned short*)(ws + 11862016);  // 10000*256 bf16 = 1280000 fl
    // total: 11862016 + 1280000 = 13142016 floats ~= 52.6 MB

    float* out_pred  = (float*)d_out;
    float* out_alpha = out_pred + (size_t)B_ * T_ * V_;

    k_transpose<<<dim3(8, 32), 256, 0, stream>>>(W_ih, WiheT, G4_, XW_, ENC_);
    k_packWda<<<64, 256, 0, stream>>>(W_dec_att, (float4*)WdaP);
    k_packWhh<<<dim3(128, 4), 256, 0, stream>>>(W_hh, (unsigned int*)WhhP);
    k_encW<<<dim3(8, 2, 64), 256, 0, stream>>>(enc, W_ih, (unsigned int*)encW);
    k_cvt<<<10000, 256, 0, stream>>>(W_out, Woutbf, V_ * DEC_);
    k_init_state<<<B_, 256, 0, stream>>>(enc, W_init_h, b_init_h, W_init_c, b_init_c, h0, c0);
    k_att1<<<B_ * 4, 256, 0, stream>>>(enc, W_enc_att, (unsigned int*)att1h);
    k_embW<<<176, 256, 0, stream>>>(caption, embedding, WiheT, b_ih, b_hh, embW);
    k_recur<<<B_, 1024, 0, stream>>>((const unsigned int*)att1h, (const float4*)WdaP, W_full,
                                     (const unsigned int*)WhhP, (const unsigned int*)encW,
                                     embW, h0, c0, Hbf, out_alpha);
    k_logits<<<dim3(79, 22), 256, 0, stream>>>(Hbf, Woutbf, b_out, out_pred);
}